// Round 4
// baseline (224.175 us; speedup 1.0000x reference)
//
#include <hip/hip_runtime.h>
#include <math.h>

// Problem constants (fixed by setup_inputs)
#define BB 512
#define TT 64
#define SS 128
#define OO 32
#define DTC 0.05f

// -DT / sqrt(S) = -0.05 / 11.313708498984761
#define NEG_DT_INVSQ (-0.004419417382415922f)
#define HALF_LOG2PI 0.9189385332046727f

typedef float f4 __attribute__((ext_vector_type(4)));

// W layout: logical (r,c) at Wf[r*128 + (c ^ PSW(r))], PSW(r)=4*((r>>3)&7).
// XOR is within a 32-float sub-block (bits 2-4 of col), preserves f4 chunks.
// Balanced bank-groups for: f4 row-contiguous build writes, col-panel (Cd)
// loads (2-way b128), sweep r/w (8 groups x 8 lanes = balanced), row-panel
// reads (full-row spread), pivot reads (8-addr broadcast).
#define PSW(r) ((((r) >> 3) & 7) << 2)

__device__ __forceinline__ f4 ld4(const float* a) { return *reinterpret_cast<const f4*>(a); }
__device__ __forceinline__ void st4(float* a, f4 v) { *reinterpret_cast<f4*>(a) = v; }

// One block (512 threads) per batch b; 512 blocks = 2 blocks/CU, 16 waves/CU.
//  phase 0: unscale p -> r (softplus), x0 (sigmoid); build W = K (row-major,
//           swizzled, f4 writes)
//  phase 1: blocked Gauss-Jordan inversion, NB=8, doctored rank-8 updates
//           (verified on HW last round; orientation-neutral) -> W = K^-1 = M
//  phase 2: double-buffered x, ONE barrier/step: thread (s=tid>>2, q=tid&3)
//           computes 32-wide partial of row s from registers, in-wave
//           shfl reduce over q; C-projection of x_t pipelined into step t+1.
__global__ __launch_bounds__(512, 4) void fused_kernel(
    const float* __restrict__ p, const float* __restrict__ A,
    const float* __restrict__ C, const float* __restrict__ d,
    const float* __restrict__ sigma_p, const float* __restrict__ my,
    const int* __restrict__ pscale, float* __restrict__ ws_partial)
{
    __shared__ __align__(16) float Wf[SS * SS];     // 64 KiB, swizzled
    __shared__ __align__(16) float PsT[8 * 12];     // PsT[j][i] = Pinv[i][j]
    __shared__ __align__(16) float xbuf[2][SS];     // double-buffered state
    __shared__ __align__(16) float rbuf[SS];        // decay rates r
    __shared__ float redsm[8];

    const int tid = threadIdx.x;
    const int b = blockIdx.x;

    // ---------------- phase 0: setup ----------------
    if (tid < SS) {
        float pv = p[b * SS + tid];
        int sc = pscale[tid];
        // amici unscale: 0=none, 1=ln, 2=log10
        float ps = (sc == 0) ? pv : ((sc == 1) ? expf(pv) : exp10f(pv));
        rbuf[tid] = fmaxf(ps, 0.0f) + log1pf(expf(-fabsf(ps)));  // softplus
        xbuf[0][tid] = 1.0f / (1.0f + expf(-ps));                // sigmoid x0
    }
    __syncthreads();

    // Build W = K row-major: K[j][i] = (i==j)*(1 + DT*r_j) - DT/sqrt(S)*A[j][i]
    // f4 chunks: m4 = chunk id; j = m4>>5, i0 = (m4&31)*4. Coalesced A reads,
    // row-contiguous swizzled f4 LDS writes (bank-balanced).
    #pragma unroll
    for (int it = 0; it < (SS * SS) / (512 * 4); ++it) {
        int m4 = it * 512 + tid;
        int j = m4 >> 5;
        int i0 = (m4 & 31) << 2;
        f4 v = NEG_DT_INVSQ * ld4(&A[j * SS + i0]);
        if (j >= i0 && j < i0 + 4) v[j - i0] += fmaf(DTC, rbuf[j], 1.0f);
        st4(&Wf[j * SS + (i0 ^ PSW(j))], v);
    }
    __syncthreads();

    // ---------------- phase 1: blocked Gauss-Jordan, NB = 8 ----------------
    const int ti = tid & 15;          // row-tile: rows 8*ti .. 8*ti+7
    const int tj = tid >> 4;          // col-chunk: cols 4*tj .. 4*tj+3
    const int swt = (ti & 7) << 2;    // PSW of this thread's 8 rows (shared)
    const int pcA = (4 * tj) ^ swt;   // phys col of own 4-col chunk

    for (int kb = 0; kb < 16; ++kb) {
        const int k0 = kb * 8;
        const int swk = (kb & 7) << 2;   // PSW of pivot rows k0..k0+7

        // Cd: doctored col-panel (pre-update W), own 8 rows x pivot 8 cols
        f4 cda[8], cdb[8];
        {
            const int qA = k0 ^ swt, qB = (k0 + 4) ^ swt;
            #pragma unroll
            for (int rr = 0; rr < 8; ++rr) {
                int base = (8 * ti + rr) * SS;
                cda[rr] = ld4(&Wf[base + qA]);
                cdb[rr] = ld4(&Wf[base + qB]);
            }
            if (ti == kb) {   // subtract identity at block rows
                #pragma unroll
                for (int rr = 0; rr < 8; ++rr) {
                    if (rr < 4) cda[rr][rr] -= 1.0f;
                    else        cdb[rr][rr - 4] -= 1.0f;
                }
            }
        }

        // wave 0: 8x8 pivot inverse via shfl-only doctored rank-1 GJ
        if (tid < 64) {
            int gi = tid >> 3, gj = tid & 7;
            float q = Wf[(k0 + gi) * SS + ((k0 + gj) ^ swk)];
            #pragma unroll
            for (int kk = 0; kk < 8; ++kk) {
                float ck = __shfl(q, (gi << 3) | kk, 64);   // P[gi][kk]
                float pr = __shfl(q, (kk << 3) | gj, 64);   // P[kk][gj]
                float pv = __shfl(q, (kk << 3) | kk, 64);   // P[kk][kk]
                float ip = 1.0f / pv;
                float ckd = ck - ((gi == kk) ? 1.0f : 0.0f);
                float prd = pr + ((gj == kk) ? 1.0f : 0.0f);
                q = fmaf(-ckd, prd * ip, q);
            }
            PsT[gj * 12 + gi] = q;   // PsT[j][i] = Pinv[i][j]
        }
        __syncthreads();   // PsT visible; W untouched so far

        // T-slice: T[i][own 4 cols] = sum_j Pinv[i][j] * (W[k0+j][c] + E)
        f4 t[8] = {f4{0,0,0,0},f4{0,0,0,0},f4{0,0,0,0},f4{0,0,0,0},
                   f4{0,0,0,0},f4{0,0,0,0},f4{0,0,0,0},f4{0,0,0,0}};
        {
            const int rc = (4 * tj) ^ swk;
            #pragma unroll
            for (int j = 0; j < 8; ++j) {
                f4 rw = ld4(&Wf[(k0 + j) * SS + rc]);
                if (tj == 2 * kb) { if (j < 4) rw[j] += 1.0f; }
                else if (tj == 2 * kb + 1) { if (j >= 4) rw[j - 4] += 1.0f; }
                f4 pa = ld4(&PsT[j * 12]);       // Pinv[0..3][j] (broadcast)
                f4 pb = ld4(&PsT[j * 12 + 4]);   // Pinv[4..7][j]
                #pragma unroll
                for (int i = 0; i < 4; ++i) {
                    t[i]     += pa[i] * rw;
                    t[i + 4] += pb[i] * rw;
                }
            }
        }
        __syncthreads();   // all row-panel reads done before sweep writes

        // sweep: W[own 8x4 tile] -= Cd * T   (disjoint tiles: no races)
        #pragma unroll
        for (int rr = 0; rr < 8; ++rr) {
            int base = (8 * ti + rr) * SS;
            f4 va = ld4(&Wf[base + pcA]);
            #pragma unroll
            for (int i = 0; i < 8; ++i) {
                float cdi = (i < 4) ? cda[rr][i] : cdb[rr][i - 4];
                va -= cdi * t[i];
            }
            st4(&Wf[base + pcA], va);
        }
        __syncthreads();   // W stable for next kb
    }
    // W now holds M = K^-1 (row-major, swizzled)

    // ---------------- phase 2: register matvec + pipelined projection ----------------
    const int s = tid >> 2, q = tid & 3;     // matvec role: row s, j-slice q
    f4 Mreg[8];                              // M[s][32q .. 32q+31]
    #pragma unroll
    for (int c = 0; c < 8; ++c)
        Mreg[c] = ld4(&Wf[s * SS + (((32 * q) + 4 * c) ^ PSW(s))]);

    const int o = tid >> 4, sub = tid & 15;  // projection role
    const f4 Cr0 = ld4(&C[o * SS + 4 * sub]);
    const f4 Cr1 = ld4(&C[o * SS + 64 + 4 * sub]);
    const float dval = d[o];
    const float sgp = sigma_p[o];
    const float isig = expf(-sgp);             // 1 / sigmay
    const float cterm = sgp + HALF_LOG2PI;     // log(sigmay) + 0.5*log(2pi)
    float lacc = 0.0f;
    const float* __restrict__ myb = my + (size_t)b * (TT * OO);

    int cur = 0;
    for (int t = 0; t < TT; ++t) {
        const float* xc = xbuf[cur];
        // x_{t+1}[s] partial over own 32 j's; c-start rotated by q so the
        // 4 broadcast addresses per ld4 land in 4 distinct bank-groups
        f4 acc = {0, 0, 0, 0};
        #pragma unroll
        for (int cc = 0; cc < 8; ++cc) {
            int c = (cc + 2 * q) & 7;
            acc += Mreg[c] * ld4(&xc[32 * q + 4 * c]);
        }
        float xn = (acc[0] + acc[1]) + (acc[2] + acc[3]);
        xn += __shfl_xor(xn, 1);
        xn += __shfl_xor(xn, 2);

        // projection of x_t (pipelined; y_t for t>=1 pairs with my[t-1])
        if (t > 0) {
            f4 pv4 = Cr0 * ld4(&xc[4 * sub]) + Cr1 * ld4(&xc[64 + 4 * sub]);
            float py = (pv4[0] + pv4[1]) + (pv4[2] + pv4[3]);
            py += __shfl_xor(py, 1);
            py += __shfl_xor(py, 2);
            py += __shfl_xor(py, 4);
            py += __shfl_xor(py, 8);
            if (sub == 0) {
                float e = (py + dval - myb[(t - 1) * OO + o]) * isig;
                lacc += fmaf(0.5f * e, e, cterm);
            }
        }

        if (q == 0) xbuf[cur ^ 1][s] = xn;
        __syncthreads();
        cur ^= 1;
    }
    // final projection: x_64 sits in xbuf[cur] (cur back to 0)
    {
        const float* xc = xbuf[cur];
        f4 pv4 = Cr0 * ld4(&xc[4 * sub]) + Cr1 * ld4(&xc[64 + 4 * sub]);
        float py = (pv4[0] + pv4[1]) + (pv4[2] + pv4[3]);
        py += __shfl_xor(py, 1);
        py += __shfl_xor(py, 2);
        py += __shfl_xor(py, 4);
        py += __shfl_xor(py, 8);
        if (sub == 0) {
            float e = (py + dval - myb[63 * OO + o]) * isig;
            lacc += fmaf(0.5f * e, e, cterm);
        }
    }

    // block-sum lacc (8 waves)
    #pragma unroll
    for (int off = 32; off >= 1; off >>= 1) lacc += __shfl_xor(lacc, off);
    if ((tid & 63) == 0) redsm[tid >> 6] = lacc;
    __syncthreads();
    if (tid == 0) {
        float ssum = 0.0f;
        #pragma unroll
        for (int i = 0; i < 8; ++i) ssum += redsm[i];
        ws_partial[b] = ssum;
    }
}

__global__ void reduce_kernel(const float* __restrict__ ws_partial,
                              float* __restrict__ out)
{
    __shared__ double sm[8];
    int tid = threadIdx.x;   // 512 threads
    double v = (double)ws_partial[tid];
    #pragma unroll
    for (int off = 32; off >= 1; off >>= 1) v += __shfl_xor(v, off);
    if ((tid & 63) == 0) sm[tid >> 6] = v;
    __syncthreads();
    if (tid == 0) {
        double s = 0.0;
        for (int i = 0; i < 8; ++i) s += sm[i];
        out[0] = (float)(-s);   // llh = -sum(Jy)
    }
}

extern "C" void kernel_launch(void* const* d_in, const int* in_sizes, int n_in,
                              void* d_out, int out_size, void* d_ws, size_t ws_size,
                              hipStream_t stream) {
    const float* p       = (const float*)d_in[0];
    const float* A       = (const float*)d_in[1];
    const float* C       = (const float*)d_in[2];
    const float* d       = (const float*)d_in[3];
    const float* sigma_p = (const float*)d_in[4];
    const float* my      = (const float*)d_in[5];
    const int*   pscale  = (const int*)d_in[6];
    float* out = (float*)d_out;
    float* wsf = (float*)d_ws;   // 512 partial sums

    fused_kernel<<<BB, 512, 0, stream>>>(p, A, C, d, sigma_p, my, pscale, wsf);
    reduce_kernel<<<1, 512, 0, stream>>>(wsf, out);
}

// Round 6
// 206.627 us; speedup vs baseline: 1.0849x; 1.0849x over previous
//
#include <hip/hip_runtime.h>
#include <math.h>

// Problem constants (fixed by setup_inputs)
#define BB 512
#define TT 64
#define SS 128
#define OO 32
#define DTC 0.05f

// -DT / sqrt(S) = -0.05 / 11.313708498984761
#define NEG_DT_INVSQ (-0.004419417382415922f)
#define HALF_LOG2PI 0.9189385332046727f

typedef float f4 __attribute__((ext_vector_type(4)));

// W layout: logical (r,c) at Wf[r*128 + (c ^ PSW(r))], PSW(r)=4*((r>>3)&7).
// XOR affects col bits 2-4 only: preserves f4 chunks, spreads the 8 rows of
// a thread-tile across the 8 bank-groups (2-way residual = free, m136).
#define PSW(r) ((((r) >> 3) & 7) << 2)

__device__ __forceinline__ f4 ld4(const float* a) { return *reinterpret_cast<const f4*>(a); }
__device__ __forceinline__ void st4(float* a, f4 v) { *reinterpret_cast<f4*>(a) = v; }

// One block (512 threads) per batch b; 512 blocks = 2 blocks/CU, 16 waves/CU.
//  phase 0: unscale p -> r (softplus), x0 (sigmoid); build W = K (row-major,
//           swizzled, f4 writes; diag insert via static-index cndmask)
//  phase 1: blocked Gauss-Jordan inversion, NB=8, doctored rank-8 updates
//           (HW-verified correct, absmax 0.0) -> W = K^-1 = M
//  phase 2: double-buffered x, ONE barrier/step. Thread (s=tid>>2, q=tid&3)
//           keeps M[s][32q..32q+31] in registers -- rotation folded into the
//           LOAD so every register index is compile-time (rule #20).
__global__ __launch_bounds__(512, 4) void fused_kernel(
    const float* __restrict__ p, const float* __restrict__ A,
    const float* __restrict__ C, const float* __restrict__ d,
    const float* __restrict__ sigma_p, const float* __restrict__ my,
    const int* __restrict__ pscale, float* __restrict__ ws_partial)
{
    __shared__ __align__(16) float Wf[SS * SS];     // 64 KiB, swizzled
    __shared__ __align__(16) float PsT[8 * 12];     // PsT[j][i] = Pinv[i][j]
    __shared__ __align__(16) float xbuf[2][SS];     // double-buffered state
    __shared__ __align__(16) float rbuf[SS];        // decay rates r
    __shared__ float redsm[8];

    const int tid = threadIdx.x;
    const int b = blockIdx.x;

    // ---------------- phase 0: setup ----------------
    if (tid < SS) {
        float pv = p[b * SS + tid];
        int sc = pscale[tid];
        // amici unscale: 0=none, 1=ln, 2=log10
        float ps = (sc == 0) ? pv : ((sc == 1) ? expf(pv) : exp10f(pv));
        rbuf[tid] = fmaxf(ps, 0.0f) + log1pf(expf(-fabsf(ps)));  // softplus
        xbuf[0][tid] = 1.0f / (1.0f + expf(-ps));                // sigmoid x0
    }
    __syncthreads();

    // Build W = K row-major: K[j][i] = (i==j)*(1 + DT*r_j) - DT/sqrt(S)*A[j][i]
    // f4 chunks: j = m4>>5, i0 = (m4&31)*4. Coalesced A reads, row-contiguous
    // swizzled f4 LDS writes. Diag insert: static element index + cndmask.
    #pragma unroll
    for (int it = 0; it < (SS * SS) / (512 * 4); ++it) {
        int m4 = it * 512 + tid;
        int j = m4 >> 5;
        int i0 = (m4 & 31) << 2;
        f4 v = NEG_DT_INVSQ * ld4(&A[j * SS + i0]);
        float diag = fmaf(DTC, rbuf[j], 1.0f);
        #pragma unroll
        for (int e = 0; e < 4; ++e)
            v[e] += (i0 + e == j) ? diag : 0.0f;
        st4(&Wf[j * SS + (i0 ^ PSW(j))], v);
    }
    __syncthreads();

    // ---------------- phase 1: blocked Gauss-Jordan, NB = 8 ----------------
    const int ti = tid & 15;          // row-tile: rows 8*ti .. 8*ti+7
    const int tj = tid >> 4;          // col-chunk: cols 4*tj .. 4*tj+3
    const int swt = (ti & 7) << 2;    // PSW of this thread's 8 rows (shared)
    const int pcA = (4 * tj) ^ swt;   // phys col of own 4-col chunk

    for (int kb = 0; kb < 16; ++kb) {
        const int k0 = kb * 8;
        const int swk = (kb & 7) << 2;   // PSW of pivot rows k0..k0+7

        // Cd: doctored col-panel (pre-update W), own 8 rows x pivot 8 cols
        f4 cda[8], cdb[8];
        {
            const int qA = k0 ^ swt, qB = (k0 + 4) ^ swt;
            #pragma unroll
            for (int rr = 0; rr < 8; ++rr) {
                int base = (8 * ti + rr) * SS;
                cda[rr] = ld4(&Wf[base + qA]);
                cdb[rr] = ld4(&Wf[base + qB]);
            }
            if (ti == kb) {   // subtract identity at block rows
                #pragma unroll
                for (int rr = 0; rr < 8; ++rr) {
                    if (rr < 4) cda[rr][rr] -= 1.0f;
                    else        cdb[rr][rr - 4] -= 1.0f;
                }
            }
        }

        // wave 0: 8x8 pivot inverse via shfl-only doctored rank-1 GJ
        if (tid < 64) {
            int gi = tid >> 3, gj = tid & 7;
            float q = Wf[(k0 + gi) * SS + ((k0 + gj) ^ swk)];
            #pragma unroll
            for (int kk = 0; kk < 8; ++kk) {
                float ck = __shfl(q, (gi << 3) | kk, 64);   // P[gi][kk]
                float pr = __shfl(q, (kk << 3) | gj, 64);   // P[kk][gj]
                float pv = __shfl(q, (kk << 3) | kk, 64);   // P[kk][kk]
                float ip = 1.0f / pv;
                float ckd = ck - ((gi == kk) ? 1.0f : 0.0f);
                float prd = pr + ((gj == kk) ? 1.0f : 0.0f);
                q = fmaf(-ckd, prd * ip, q);
            }
            PsT[gj * 12 + gi] = q;   // PsT[j][i] = Pinv[i][j]
        }
        __syncthreads();   // PsT visible; W untouched so far

        // T-slice: T[i][own 4 cols] = sum_j Pinv[i][j] * (W[k0+j][c] + E)
        f4 t[8] = {f4{0,0,0,0},f4{0,0,0,0},f4{0,0,0,0},f4{0,0,0,0},
                   f4{0,0,0,0},f4{0,0,0,0},f4{0,0,0,0},f4{0,0,0,0}};
        {
            const int rc = (4 * tj) ^ swk;
            #pragma unroll
            for (int j = 0; j < 8; ++j) {
                f4 rw = ld4(&Wf[(k0 + j) * SS + rc]);
                if (tj == 2 * kb) { if (j < 4) rw[j] += 1.0f; }
                else if (tj == 2 * kb + 1) { if (j >= 4) rw[j - 4] += 1.0f; }
                f4 pa = ld4(&PsT[j * 12]);       // Pinv[0..3][j] (broadcast)
                f4 pb = ld4(&PsT[j * 12 + 4]);   // Pinv[4..7][j]
                #pragma unroll
                for (int i = 0; i < 4; ++i) {
                    t[i]     += pa[i] * rw;
                    t[i + 4] += pb[i] * rw;
                }
            }
        }
        __syncthreads();   // all row-panel reads done before sweep writes

        // sweep: W[own 8x4 tile] -= Cd * T   (disjoint tiles: no races)
        #pragma unroll
        for (int rr = 0; rr < 8; ++rr) {
            int base = (8 * ti + rr) * SS;
            f4 va = ld4(&Wf[base + pcA]);
            #pragma unroll
            for (int i = 0; i < 8; ++i) {
                float cdi = (i < 4) ? cda[rr][i] : cdb[rr][i - 4];
                va -= cdi * t[i];
            }
            st4(&Wf[base + pcA], va);
        }
        __syncthreads();   // W stable for next kb
    }
    // W now holds M = K^-1 (row-major, swizzled)

    // ---------------- phase 2: register matvec + pipelined projection ----------------
    const int s = tid >> 2, q = tid & 3;     // matvec role: row s, j-slice q
    // Mreg[i] holds M[s][32q + 4*((i+2q)&7) .. +3]: rotation folded into the
    // load (runtime ADDRESS, static register index -- no scratch).
    f4 Mreg[8];
    #pragma unroll
    for (int i = 0; i < 8; ++i) {
        int ci = 4 * ((i + 2 * q) & 7);
        Mreg[i] = ld4(&Wf[s * SS + ((32 * q + ci) ^ PSW(s))]);
    }

    const int o = tid >> 4, sub = tid & 15;  // projection role
    const f4 Cr0 = ld4(&C[o * SS + 4 * sub]);
    const f4 Cr1 = ld4(&C[o * SS + 64 + 4 * sub]);
    const float dval = d[o];
    const float sgp = sigma_p[o];
    const float isig = expf(-sgp);             // 1 / sigmay
    const float cterm = sgp + HALF_LOG2PI;     // log(sigmay) + 0.5*log(2pi)
    float lacc = 0.0f;
    const float* __restrict__ myb = my + (size_t)b * (TT * OO);

    int cur = 0;
    for (int t = 0; t < TT; ++t) {
        const float* xc = xbuf[cur];
        // x_{t+1}[s] partial over own 32 j's; per-instruction the 4 q-groups
        // read 4 rotated chunks -> 4 distinct bank-groups, conflict-free.
        f4 acc = {0, 0, 0, 0};
        #pragma unroll
        for (int cc = 0; cc < 8; ++cc) {
            int cx = 32 * q + 4 * ((cc + 2 * q) & 7);
            acc += Mreg[cc] * ld4(&xc[cx]);
        }
        float xn = (acc[0] + acc[1]) + (acc[2] + acc[3]);
        xn += __shfl_xor(xn, 1);
        xn += __shfl_xor(xn, 2);

        // projection of x_t (pipelined; y_t for t>=1 pairs with my[t-1])
        if (t > 0) {
            f4 pv4 = Cr0 * ld4(&xc[4 * sub]) + Cr1 * ld4(&xc[64 + 4 * sub]);
            float py = (pv4[0] + pv4[1]) + (pv4[2] + pv4[3]);
            py += __shfl_xor(py, 1);
            py += __shfl_xor(py, 2);
            py += __shfl_xor(py, 4);
            py += __shfl_xor(py, 8);
            if (sub == 0) {
                float e = (py + dval - myb[(t - 1) * OO + o]) * isig;
                lacc += fmaf(0.5f * e, e, cterm);
            }
        }

        if (q == 0) xbuf[cur ^ 1][s] = xn;
        __syncthreads();
        cur ^= 1;
    }
    // final projection: x_64 sits in xbuf[cur]
    {
        const float* xc = xbuf[cur];
        f4 pv4 = Cr0 * ld4(&xc[4 * sub]) + Cr1 * ld4(&xc[64 + 4 * sub]);
        float py = (pv4[0] + pv4[1]) + (pv4[2] + pv4[3]);
        py += __shfl_xor(py, 1);
        py += __shfl_xor(py, 2);
        py += __shfl_xor(py, 4);
        py += __shfl_xor(py, 8);
        if (sub == 0) {
            float e = (py + dval - myb[63 * OO + o]) * isig;
            lacc += fmaf(0.5f * e, e, cterm);
        }
    }

    // block-sum lacc (8 waves)
    #pragma unroll
    for (int off = 32; off >= 1; off >>= 1) lacc += __shfl_xor(lacc, off);
    if ((tid & 63) == 0) redsm[tid >> 6] = lacc;
    __syncthreads();
    if (tid == 0) {
        float ssum = 0.0f;
        #pragma unroll
        for (int i = 0; i < 8; ++i) ssum += redsm[i];
        ws_partial[b] = ssum;
    }
}

__global__ void reduce_kernel(const float* __restrict__ ws_partial,
                              float* __restrict__ out)
{
    __shared__ double sm[8];
    int tid = threadIdx.x;   // 512 threads
    double v = (double)ws_partial[tid];
    #pragma unroll
    for (int off = 32; off >= 1; off >>= 1) v += __shfl_xor(v, off);
    if ((tid & 63) == 0) sm[tid >> 6] = v;
    __syncthreads();
    if (tid == 0) {
        double s = 0.0;
        for (int i = 0; i < 8; ++i) s += sm[i];
        out[0] = (float)(-s);   // llh = -sum(Jy)
    }
}

extern "C" void kernel_launch(void* const* d_in, const int* in_sizes, int n_in,
                              void* d_out, int out_size, void* d_ws, size_t ws_size,
                              hipStream_t stream) {
    const float* p       = (const float*)d_in[0];
    const float* A       = (const float*)d_in[1];
    const float* C       = (const float*)d_in[2];
    const float* d       = (const float*)d_in[3];
    const float* sigma_p = (const float*)d_in[4];
    const float* my      = (const float*)d_in[5];
    const int*   pscale  = (const int*)d_in[6];
    float* out = (float*)d_out;
    float* wsf = (float*)d_ws;   // 512 partial sums

    fused_kernel<<<BB, 512, 0, stream>>>(p, A, C, d, sigma_p, my, pscale, wsf);
    reduce_kernel<<<1, 512, 0, stream>>>(wsf, out);
}